// Round 2
// baseline (1815.564 us; speedup 1.0000x reference)
//
#include <hip/hip_runtime.h>
#include <hip/hip_bf16.h>
#include <math.h>

#define HIDDIM 128
#define MT 64

__device__ inline float gelu_f(float x) {
  // jax.nn.gelu default approximate=True (tanh form)
  float x3 = x * x * x;
  return 0.5f * x * (1.0f + tanhf(0.7978845608028654f * (x + 0.044715f * x3)));
}

// Detect whether float tensors are fp32 (flag=1) or bf16 (flag=0) by
// interpreting the first 16KB of x_t as bf16: fp32 low-halves decode to
// huge/NaN exponents ~25% of the time; genuine bf16 N(0,1) data never does.
__global__ void detect_dtype(const unsigned short* __restrict__ raw, int* __restrict__ flag) {
  __shared__ int cnt;
  if (threadIdx.x == 0) cnt = 0;
  __syncthreads();
  int c = 0;
  for (int i = threadIdx.x; i < 8192; i += 256) {
    int ex = (raw[i] >> 7) & 0xFF;
    if (ex >= 0xC0) c++;   // |v| >= 2^65 as bf16 -> impossible for real data
  }
  atomicAdd(&cnt, c);
  __syncthreads();
  if (threadIdx.x == 0) flag[0] = (cnt > 64) ? 1 : 0;
}

__global__ void cvt_to_f32(const void* __restrict__ in, float* __restrict__ out,
                           int n, const int* __restrict__ flag) {
  int i = blockIdx.x * 256 + threadIdx.x;
  if (i < n) {
    out[i] = flag[0] ? ((const float*)in)[i]
                     : __bfloat162float(((const __hip_bfloat16*)in)[i]);
  }
}

// C[M x 128] = act( [A1 | A2][M x (K1+K2)] @ W[(K1+K2) x 128] + bias ), all fp32
__global__ __launch_bounds__(256) void gemm_k(
    const float* __restrict__ A1, int K1,
    const float* __restrict__ A2, int K2,
    const float* __restrict__ W,
    const float* __restrict__ bias,
    float* __restrict__ C, int M, int act) {
  const int K = K1 + K2;
  __shared__ float As[MT][32];
  __shared__ float Ws[32][HIDDIM];
  const int m0 = blockIdx.x * MT;
  const int t = threadIdx.x;
  const int cg = t & 31;   // 4 cols starting at cg*4
  const int rg = t >> 5;   // 8 rows starting at rg*8
  float acc[8][4] = {};
  for (int k0 = 0; k0 < K; k0 += 32) {
#pragma unroll
    for (int i = 0; i < 8; ++i) {  // 64x32 A tile
      int flat = t + i * 256;
      int r = flat >> 5, kk = flat & 31;
      int gr = m0 + r, gk = k0 + kk;
      float v = 0.f;
      if (gr < M) v = (gk < K1) ? A1[gr * K1 + gk] : A2[gr * K2 + (gk - K1)];
      As[r][kk] = v;
    }
#pragma unroll
    for (int i = 0; i < 16; ++i) {  // 32x128 W tile
      int flat = t + i * 256;
      int kk = flat >> 7, c = flat & 127;
      Ws[kk][c] = W[(k0 + kk) * HIDDIM + c];
    }
    __syncthreads();
#pragma unroll
    for (int kk = 0; kk < 32; ++kk) {
      const float4 w = ((const float4*)&Ws[kk][0])[cg];
#pragma unroll
      for (int r = 0; r < 8; ++r) {
        float a = As[rg * 8 + r][kk];
        acc[r][0] = fmaf(a, w.x, acc[r][0]);
        acc[r][1] = fmaf(a, w.y, acc[r][1]);
        acc[r][2] = fmaf(a, w.z, acc[r][2]);
        acc[r][3] = fmaf(a, w.w, acc[r][3]);
      }
    }
    __syncthreads();
  }
#pragma unroll
  for (int r = 0; r < 8; ++r) {
    int gr = m0 + rg * 8 + r;
    if (gr < M) {
#pragma unroll
      for (int c = 0; c < 4; ++c) {
        int col = cg * 4 + c;
        float v = acc[r][c] + bias[col];
        if (act) v = gelu_f(v);
        C[gr * HIDDIM + col] = v;
      }
    }
  }
}

__global__ void count_deg(const int* __restrict__ dst, int* __restrict__ deg, int E) {
  int e = blockIdx.x * 256 + threadIdx.x;
  if (e < E) atomicAdd(&deg[dst[e]], 1);
}

// Single-block exclusive scan of deg[0..N) -> rowptr[0..N], cursor copy.
__global__ __launch_bounds__(1024) void scan_deg(const int* __restrict__ deg,
                                                 int* __restrict__ rowptr,
                                                 int* __restrict__ cursor, int N) {
  __shared__ int buf[1024];
  __shared__ int carry;
  if (threadIdx.x == 0) carry = 0;
  __syncthreads();
  for (int base = 0; base < N; base += 1024) {
    int i = base + threadIdx.x;
    int v = (i < N) ? deg[i] : 0;
    buf[threadIdx.x] = v;
    __syncthreads();
    for (int off = 1; off < 1024; off <<= 1) {
      int add = (threadIdx.x >= (unsigned)off) ? buf[threadIdx.x - off] : 0;
      __syncthreads();
      buf[threadIdx.x] += add;
      __syncthreads();
    }
    int excl = buf[threadIdx.x] - v + carry;
    if (i < N) { rowptr[i] = excl; cursor[i] = excl; }
    __syncthreads();
    if (threadIdx.x == 0) carry += buf[1023];
    __syncthreads();
  }
  if (threadIdx.x == 0) rowptr[N] = carry;
}

__global__ void place_edges(const int* __restrict__ src, const int* __restrict__ dst,
                            int* __restrict__ cursor, int* __restrict__ colsrc, int E) {
  int e = blockIdx.x * 256 + threadIdx.x;
  if (e < E) {
    int pos = atomicAdd(&cursor[dst[e]], 1);
    colsrc[pos] = src[e];
  }
}

// One wave per destination node: online-softmax GATv2 aggregation.
// Lane covers features f0=lane*2, f0+1. Heads are 32-feature groups -> 16-lane groups.
__global__ __launch_bounds__(256) void gat_agg(
    const float* __restrict__ fs, const float* __restrict__ fd,
    const int* __restrict__ rowptr, const int* __restrict__ colsrc,
    const float* __restrict__ attn,   // [128] = [NH][HD]
    const float* __restrict__ bout,   // [128]
    float* __restrict__ hout, int N) {
  int wave = threadIdx.x >> 6;
  int lane = threadIdx.x & 63;
  int n = blockIdx.x * 4 + wave;
  if (n >= N) return;
  int f0 = lane * 2;
  float2 fdv = *(const float2*)&fd[n * HIDDIM + f0];
  float a0 = attn[f0];
  float a1 = attn[f0 + 1];
  int e0 = rowptr[n], e1 = rowptr[n + 1];
  float m = -INFINITY, s = 0.f, accx = 0.f, accy = 0.f;
  for (int e = e0; e < e1; ++e) {
    int sidx = colsrc[e];
    float2 fsv = *(const float2*)&fs[sidx * HIDDIM + f0];
    float vx = fsv.x + fdv.x; vx = vx > 0.f ? vx : 0.2f * vx;
    float vy = fsv.y + fdv.y; vy = vy > 0.f ? vy : 0.2f * vy;
    float l = fmaf(vx, a0, vy * a1);
    // sum over the 16 lanes of this head (butterfly -> all lanes hold the sum)
    l += __shfl_xor(l, 1);
    l += __shfl_xor(l, 2);
    l += __shfl_xor(l, 4);
    l += __shfl_xor(l, 8);
    float nm = fmaxf(m, l);
    float fac = __expf(m - nm);   // 0 on first edge (m = -inf)
    float p = __expf(l - nm);
    s = s * fac + p;
    accx = accx * fac + p * fsv.x;
    accy = accy * fac + p * fsv.y;
    m = nm;
  }
  float inv = 1.f / (s + 1e-9f);
  float ox = accx * inv + bout[f0];
  float oy = accy * inv + bout[f0 + 1];
  hout[n * HIDDIM + f0] = gelu_f(ox);
  hout[n * HIDDIM + f0 + 1] = gelu_f(oy);
}

// Write both outputs (out, h) in fp32 or bf16 per flag.
__global__ void store_out(const float* __restrict__ og, const float* __restrict__ h,
                          void* __restrict__ dout, int n, const int* __restrict__ flag) {
  int i = blockIdx.x * 256 + threadIdx.x;
  if (i >= n) return;
  if (flag[0]) {
    ((float*)dout)[i] = og[i];
    ((float*)dout)[n + i] = h[i];
  } else {
    ((__hip_bfloat16*)dout)[i] = __float2bfloat16(og[i]);
    ((__hip_bfloat16*)dout)[n + i] = __float2bfloat16(h[i]);
  }
}

// packed fp32 param offsets (floats)
#define OFF_W_INIT    0
#define OFF_B_INIT    32768
#define OFF_WSRC_DOWN 32896
#define OFF_BSRC_DOWN 65664
#define OFF_WDST_DOWN 65920
#define OFF_BDST_DOWN 98688
#define OFF_ATTN_DOWN 98944
#define OFF_BOUT_DOWN 99200
#define OFF_WSRC_MID  99456
#define OFF_BSRC_MID  115840
#define OFF_WDST_MID  115968
#define OFF_BDST_MID  132352
#define OFF_ATTN_MID  132480
#define OFF_BOUT_MID  132608
#define OFF_WSRC_UP   132736
#define OFF_BSRC_UP   198272
#define OFF_WDST_UP   198528
#define OFF_BDST_UP   264064
#define OFF_ATTN_UP   264320
#define OFF_BOUT_UP   264576
#define OFF_W_FIN     264832
#define OFF_B_FIN     281216
#define PARAMS_TOTAL  281344

extern "C" void kernel_launch(void* const* d_in, const int* in_sizes, int n_in,
                              void* d_out, int out_size, void* d_ws, size_t ws_size,
                              hipStream_t stream) {
  const int N = in_sizes[1] / HIDDIM;   // time_embed is [N,128]
  const int E = in_sizes[2];
  const int* src = (const int*)d_in[2];
  const int* dst = (const int*)d_in[3];

  // workspace carve: small/early stuff first, big fp32 buffers last
  char* p = (char*)d_ws;
  auto carve = [&](size_t bytes) {
    void* r = (void*)p;
    p += (bytes + 255) & ~(size_t)255;
    return r;
  };
  int* flag     = (int*)carve(256);
  float* params = (float*)carve((size_t)PARAMS_TOTAL * 4);
  int* deg      = (int*)carve((size_t)N * 4);
  int* rowptr   = (int*)carve((size_t)(N + 1) * 4);
  int* cursor   = (int*)carve((size_t)N * 4);
  int* colsrc   = (int*)carve((size_t)E * 4);
  float* h      = (float*)carve((size_t)N * HIDDIM * 4);
  float* skip0  = (float*)carve((size_t)N * HIDDIM * 4);
  float* skip1  = (float*)carve((size_t)N * HIDDIM * 4);
  float* fs     = (float*)carve((size_t)N * HIDDIM * 4);  // aliases xc pre-layers
  float* fd     = (float*)carve((size_t)N * HIDDIM * 4);  // aliases tc pre-layers

  // 1. dtype flag
  detect_dtype<<<1, 256, 0, stream>>>((const unsigned short*)d_in[0], flag);

  // 2. stage all float params to packed fp32
  struct Item { int idx; int off; int n; };
  static const Item items[] = {
    {4,  OFF_W_INIT,    32768}, {5,  OFF_B_INIT,    128},
    {6,  OFF_WSRC_DOWN, 32768}, {7,  OFF_BSRC_DOWN, 256},
    {8,  OFF_WDST_DOWN, 32768}, {9,  OFF_BDST_DOWN, 256},
    {10, OFF_ATTN_DOWN, 256},   {11, OFF_BOUT_DOWN, 256},
    {12, OFF_WSRC_MID,  16384}, {13, OFF_BSRC_MID,  128},
    {14, OFF_WDST_MID,  16384}, {15, OFF_BDST_MID,  128},
    {16, OFF_ATTN_MID,  128},   {17, OFF_BOUT_MID,  128},
    {18, OFF_WSRC_UP,   65536}, {19, OFF_BSRC_UP,   256},
    {20, OFF_WDST_UP,   65536}, {21, OFF_BDST_UP,   256},
    {22, OFF_ATTN_UP,   256},   {23, OFF_BOUT_UP,   256},
    {24, OFF_W_FIN,     16384}, {25, OFF_B_FIN,     128},
  };
  for (const Item& it : items) {
    cvt_to_f32<<<(it.n + 255) / 256, 256, 0, stream>>>(d_in[it.idx], params + it.off, it.n, flag);
  }
  // stage x_t, time_embed into fs/fd (consumed by the init GEMM before reuse)
  float* xc = fs;
  float* tc = fd;
  cvt_to_f32<<<(N * HIDDIM + 255) / 256, 256, 0, stream>>>(d_in[0], xc, N * HIDDIM, flag);
  cvt_to_f32<<<(N * HIDDIM + 255) / 256, 256, 0, stream>>>(d_in[1], tc, N * HIDDIM, flag);

  // 3. CSR by dst (rebuilt every call; ws is re-poisoned)
  hipMemsetAsync(deg, 0, (size_t)N * 4, stream);
  count_deg<<<(E + 255) / 256, 256, 0, stream>>>(dst, deg, E);
  scan_deg<<<1, 1024, 0, stream>>>(deg, rowptr, cursor, N);
  place_edges<<<(E + 255) / 256, 256, 0, stream>>>(src, dst, cursor, colsrc, E);

  dim3 gb((N + MT - 1) / MT);
  dim3 ga((N + 3) / 4);
  const float* P = params;

  // h = gelu([x_t | time_embed] @ W_init + b_init)
  gemm_k<<<gb, 256, 0, stream>>>(xc, 128, tc, 128, P + OFF_W_INIT, P + OFF_B_INIT, h, N, 1);

  auto gat_layer = [&](const float* ha, const float* hb, int Ka, int Kb,
                       const float* Wsrc, const float* bsrc,
                       const float* Wdst, const float* bdst,
                       const float* attn, const float* bout, float* hout) {
    gemm_k<<<gb, 256, 0, stream>>>(ha, Ka, hb, Kb, Wsrc, bsrc, fs, N, 0);
    gemm_k<<<gb, 256, 0, stream>>>(ha, Ka, hb, Kb, Wdst, bdst, fd, N, 0);
    gat_agg<<<ga, 256, 0, stream>>>(fs, fd, rowptr, colsrc, attn, bout, hout, N);
  };

  // down 0
  hipMemcpyAsync(skip0, h, (size_t)N * HIDDIM * 4, hipMemcpyDeviceToDevice, stream);
  gat_layer(h, nullptr, 128, 0, P + OFF_WSRC_DOWN, P + OFF_BSRC_DOWN,
            P + OFF_WDST_DOWN, P + OFF_BDST_DOWN, P + OFF_ATTN_DOWN, P + OFF_BOUT_DOWN, h);
  // down 1
  hipMemcpyAsync(skip1, h, (size_t)N * HIDDIM * 4, hipMemcpyDeviceToDevice, stream);
  gat_layer(h, nullptr, 128, 0, P + OFF_WSRC_DOWN + 16384, P + OFF_BSRC_DOWN + 128,
            P + OFF_WDST_DOWN + 16384, P + OFF_BDST_DOWN + 128,
            P + OFF_ATTN_DOWN + 128, P + OFF_BOUT_DOWN + 128, h);
  // mid
  gat_layer(h, nullptr, 128, 0, P + OFF_WSRC_MID, P + OFF_BSRC_MID,
            P + OFF_WDST_MID, P + OFF_BDST_MID, P + OFF_ATTN_MID, P + OFF_BOUT_MID, h);
  // up 0: concat([h, skips[1]])
  gat_layer(h, skip1, 128, 128, P + OFF_WSRC_UP, P + OFF_BSRC_UP,
            P + OFF_WDST_UP, P + OFF_BDST_UP, P + OFF_ATTN_UP, P + OFF_BOUT_UP, h);
  // up 1: concat([h, skips[0]])
  gat_layer(h, skip0, 128, 128, P + OFF_WSRC_UP + 32768, P + OFF_BSRC_UP + 128,
            P + OFF_WDST_UP + 32768, P + OFF_BDST_UP + 128,
            P + OFF_ATTN_UP + 128, P + OFF_BOUT_UP + 128, h);

  // out = h @ W_fin + b_fin -> skip1 (dead), then store (out, h) per dtype flag
  float* outg = skip1;
  gemm_k<<<gb, 256, 0, stream>>>(h, 128, nullptr, 0, P + OFF_W_FIN, P + OFF_B_FIN, outg, N, 0);
  store_out<<<(N * HIDDIM + 255) / 256, 256, 0, stream>>>(outg, h, d_out, N * HIDDIM, flag);
}

// Round 7
// 1556.632 us; speedup vs baseline: 1.1663x; 1.1663x over previous
//
#include <hip/hip_runtime.h>
#include <hip/hip_bf16.h>
#include <math.h>

#define HIDDIM 128
#define MT 64

__device__ inline float gelu_f(float x) {
  // jax.nn.gelu default approximate=True (tanh form)
  float x3 = x * x * x;
  return 0.5f * x * (1.0f + tanhf(0.7978845608028654f * (x + 0.044715f * x3)));
}

// Detect whether float tensors are fp32 (flag=1) or bf16 (flag=0) by
// interpreting the first 16KB of x_t as bf16: fp32 low-halves decode to
// huge/NaN exponents ~25% of the time; genuine bf16 N(0,1) data never does.
__global__ void detect_dtype(const unsigned short* __restrict__ raw, int* __restrict__ flag) {
  __shared__ int cnt;
  if (threadIdx.x == 0) cnt = 0;
  __syncthreads();
  int c = 0;
  for (int i = threadIdx.x; i < 8192; i += 256) {
    int ex = (raw[i] >> 7) & 0xFF;
    if (ex >= 0xC0) c++;   // |v| >= 2^65 as bf16 -> impossible for real data
  }
  atomicAdd(&cnt, c);
  __syncthreads();
  if (threadIdx.x == 0) flag[0] = (cnt > 64) ? 1 : 0;
}

__global__ void cvt_to_f32(const void* __restrict__ in, float* __restrict__ out,
                           int n, const int* __restrict__ flag) {
  int i = blockIdx.x * 256 + threadIdx.x;
  if (i < n) {
    out[i] = flag[0] ? ((const float*)in)[i]
                     : __bfloat162float(((const __hip_bfloat16*)in)[i]);
  }
}

// C[M x 128] = act( [A1 | A2][M x (K1+K2)] @ W[(K1+K2) x 128] + bias ), all fp32
__global__ __launch_bounds__(256) void gemm_k(
    const float* __restrict__ A1, int K1,
    const float* __restrict__ A2, int K2,
    const float* __restrict__ W,
    const float* __restrict__ bias,
    float* __restrict__ C, int M, int act) {
  const int K = K1 + K2;
  __shared__ float As[MT][32];
  __shared__ float Ws[32][HIDDIM];
  const int m0 = blockIdx.x * MT;
  const int t = threadIdx.x;
  const int cg = t & 31;   // 4 cols starting at cg*4
  const int rg = t >> 5;   // 8 rows starting at rg*8
  float acc[8][4] = {};
  for (int k0 = 0; k0 < K; k0 += 32) {
#pragma unroll
    for (int i = 0; i < 8; ++i) {  // 64x32 A tile
      int flat = t + i * 256;
      int r = flat >> 5, kk = flat & 31;
      int gr = m0 + r, gk = k0 + kk;
      float v = 0.f;
      if (gr < M) v = (gk < K1) ? A1[gr * K1 + gk] : A2[gr * K2 + (gk - K1)];
      As[r][kk] = v;
    }
#pragma unroll
    for (int i = 0; i < 16; ++i) {  // 32x128 W tile
      int flat = t + i * 256;
      int kk = flat >> 7, c = flat & 127;
      Ws[kk][c] = W[(k0 + kk) * HIDDIM + c];
    }
    __syncthreads();
#pragma unroll
    for (int kk = 0; kk < 32; ++kk) {
      const float4 w = ((const float4*)&Ws[kk][0])[cg];
#pragma unroll
      for (int r = 0; r < 8; ++r) {
        float a = As[rg * 8 + r][kk];
        acc[r][0] = fmaf(a, w.x, acc[r][0]);
        acc[r][1] = fmaf(a, w.y, acc[r][1]);
        acc[r][2] = fmaf(a, w.z, acc[r][2]);
        acc[r][3] = fmaf(a, w.w, acc[r][3]);
      }
    }
    __syncthreads();
  }
#pragma unroll
  for (int r = 0; r < 8; ++r) {
    int gr = m0 + rg * 8 + r;
    if (gr < M) {
#pragma unroll
      for (int c = 0; c < 4; ++c) {
        int col = cg * 4 + c;
        float v = acc[r][c] + bias[col];
        if (act) v = gelu_f(v);
        C[gr * HIDDIM + col] = v;
      }
    }
  }
}

__global__ void count_deg(const int* __restrict__ dst, int* __restrict__ deg, int E) {
  int e = blockIdx.x * 256 + threadIdx.x;
  if (e < E) atomicAdd(&deg[dst[e]], 1);
}

// Single-block exclusive scan of deg[0..N) -> rowptr[0..N], cursor copy.
__global__ __launch_bounds__(1024) void scan_deg(const int* __restrict__ deg,
                                                 int* __restrict__ rowptr,
                                                 int* __restrict__ cursor, int N) {
  __shared__ int buf[1024];
  __shared__ int carry;
  if (threadIdx.x == 0) carry = 0;
  __syncthreads();
  for (int base = 0; base < N; base += 1024) {
    int i = base + threadIdx.x;
    int v = (i < N) ? deg[i] : 0;
    buf[threadIdx.x] = v;
    __syncthreads();
    for (int off = 1; off < 1024; off <<= 1) {
      int add = (threadIdx.x >= (unsigned)off) ? buf[threadIdx.x - off] : 0;
      __syncthreads();
      buf[threadIdx.x] += add;
      __syncthreads();
    }
    int excl = buf[threadIdx.x] - v + carry;
    if (i < N) { rowptr[i] = excl; cursor[i] = excl; }
    __syncthreads();
    if (threadIdx.x == 0) carry += buf[1023];
    __syncthreads();
  }
  if (threadIdx.x == 0) rowptr[N] = carry;
}

__global__ void place_edges(const int* __restrict__ src, const int* __restrict__ dst,
                            int* __restrict__ cursor, int* __restrict__ colsrc, int E) {
  int e = blockIdx.x * 256 + threadIdx.x;
  if (e < E) {
    int pos = atomicAdd(&cursor[dst[e]], 1);
    colsrc[pos] = src[e];
  }
}

// ---------------- NEW GATv2 aggregation (the single change under test) ----------
// One wave per dst node. Half-wave h handles edges 4it+h and 4it+2+h.
// Lane covers 4 features fb=(lane&31)*4 (one head per lane group of 8).
// Softmax without max-shift; logits clamped <=60 so exp can never overflow.
__global__ __launch_bounds__(256) void gat_agg(
    const float* __restrict__ fs, const float* __restrict__ fd,
    const int* __restrict__ rowptr, const int* __restrict__ colsrc,
    const float* __restrict__ attn,   // [128] fp32 (staged params)
    const float* __restrict__ bout,   // [128] fp32
    float* __restrict__ hout, int N, int E) {
  int wv = threadIdx.x >> 6, lane = threadIdx.x & 63;
  int n = blockIdx.x * 4 + wv;
  if (n >= N) return;
  int half = lane >> 5;
  int fb = (lane & 31) * 4;
  float4 fdv = *(const float4*)&fd[(size_t)n * HIDDIM + fb];
  float a0 = attn[fb], a1 = attn[fb + 1], a2 = attn[fb + 2], a3 = attn[fb + 3];
  int e0 = rowptr[n], e1 = rowptr[n + 1];
  e0 = max(0, min(e0, E));
  e1 = max(e0, min(e1, E));
  float s = 0.f, ax = 0.f, ay = 0.f, az = 0.f, aw = 0.f;
  for (int c0 = e0; c0 < e1; c0 += 64) {
    int cn = min(64, e1 - c0);
    int myidx = (lane < cn) ? colsrc[c0 + lane] : 0;
    myidx = ((unsigned)myidx < (unsigned)N) ? myidx : 0;  // defensive clamp
    int iters = (cn + 3) >> 2;
    for (int it = 0; it < iters; ++it) {
      int jA = 4 * it + half;
      int jB = jA + 2;
      int sA = __shfl(myidx, min(jA, cn - 1));
      int sB = __shfl(myidx, min(jB, cn - 1));
      float4 fA = *(const float4*)&fs[(size_t)sA * HIDDIM + fb];
      float4 fB = *(const float4*)&fs[(size_t)sB * HIDDIM + fb];
      float v0, v1, v2, v3, lA, lB;
      v0 = fA.x + fdv.x; v0 = v0 > 0.f ? v0 : 0.2f * v0;
      v1 = fA.y + fdv.y; v1 = v1 > 0.f ? v1 : 0.2f * v1;
      v2 = fA.z + fdv.z; v2 = v2 > 0.f ? v2 : 0.2f * v2;
      v3 = fA.w + fdv.w; v3 = v3 > 0.f ? v3 : 0.2f * v3;
      lA = fmaf(v0, a0, fmaf(v1, a1, fmaf(v2, a2, v3 * a3)));
      v0 = fB.x + fdv.x; v0 = v0 > 0.f ? v0 : 0.2f * v0;
      v1 = fB.y + fdv.y; v1 = v1 > 0.f ? v1 : 0.2f * v1;
      v2 = fB.z + fdv.z; v2 = v2 > 0.f ? v2 : 0.2f * v2;
      v3 = fB.w + fdv.w; v3 = v3 > 0.f ? v3 : 0.2f * v3;
      lB = fmaf(v0, a0, fmaf(v1, a1, fmaf(v2, a2, v3 * a3)));
      // head dot: sum over the 8 lanes of this head (stays within half-wave)
      lA += __shfl_xor(lA, 1); lA += __shfl_xor(lA, 2); lA += __shfl_xor(lA, 4);
      lB += __shfl_xor(lB, 1); lB += __shfl_xor(lB, 2); lB += __shfl_xor(lB, 4);
      lA = fminf(lA, 60.f);
      lB = fminf(lB, 60.f);
      float pA = (jA < cn) ? __expf(lA) : 0.f;
      float pB = (jB < cn) ? __expf(lB) : 0.f;
      s += pA + pB;
      ax = fmaf(pA, fA.x, fmaf(pB, fB.x, ax));
      ay = fmaf(pA, fA.y, fmaf(pB, fB.y, ay));
      az = fmaf(pA, fA.z, fmaf(pB, fB.z, az));
      aw = fmaf(pA, fA.w, fmaf(pB, fB.w, aw));
    }
  }
  // combine the two half-waves
  s += __shfl_xor(s, 32);
  ax += __shfl_xor(ax, 32); ay += __shfl_xor(ay, 32);
  az += __shfl_xor(az, 32); aw += __shfl_xor(aw, 32);
  if (half == 0) {
    float inv = 1.f / (s + 1e-9f);
    float o0 = gelu_f(fmaf(ax, inv, bout[fb]));
    float o1 = gelu_f(fmaf(ay, inv, bout[fb + 1]));
    float o2 = gelu_f(fmaf(az, inv, bout[fb + 2]));
    float o3 = gelu_f(fmaf(aw, inv, bout[fb + 3]));
    *(float4*)&hout[(size_t)n * HIDDIM + fb] = make_float4(o0, o1, o2, o3);
  }
}

// Write both outputs (out, h) in fp32 or bf16 per flag.
__global__ void store_out(const float* __restrict__ og, const float* __restrict__ h,
                          void* __restrict__ dout, int n, const int* __restrict__ flag) {
  int i = blockIdx.x * 256 + threadIdx.x;
  if (i >= n) return;
  if (flag[0]) {
    ((float*)dout)[i] = og[i];
    ((float*)dout)[n + i] = h[i];
  } else {
    ((__hip_bfloat16*)dout)[i] = __float2bfloat16(og[i]);
    ((__hip_bfloat16*)dout)[n + i] = __float2bfloat16(h[i]);
  }
}

// packed fp32 param offsets (floats)
#define OFF_W_INIT    0
#define OFF_B_INIT    32768
#define OFF_WSRC_DOWN 32896
#define OFF_BSRC_DOWN 65664
#define OFF_WDST_DOWN 65920
#define OFF_BDST_DOWN 98688
#define OFF_ATTN_DOWN 98944
#define OFF_BOUT_DOWN 99200
#define OFF_WSRC_MID  99456
#define OFF_BSRC_MID  115840
#define OFF_WDST_MID  115968
#define OFF_BDST_MID  132352
#define OFF_ATTN_MID  132480
#define OFF_BOUT_MID  132608
#define OFF_WSRC_UP   132736
#define OFF_BSRC_UP   198272
#define OFF_WDST_UP   198528
#define OFF_BDST_UP   264064
#define OFF_ATTN_UP   264320
#define OFF_BOUT_UP   264576
#define OFF_W_FIN     264832
#define OFF_B_FIN     281216
#define PARAMS_TOTAL  281344

extern "C" void kernel_launch(void* const* d_in, const int* in_sizes, int n_in,
                              void* d_out, int out_size, void* d_ws, size_t ws_size,
                              hipStream_t stream) {
  const int N = in_sizes[1] / HIDDIM;   // time_embed is [N,128]
  const int E = in_sizes[2];
  const int* src = (const int*)d_in[2];
  const int* dst = (const int*)d_in[3];

  // workspace carve: small/early stuff first, big fp32 buffers last
  char* p = (char*)d_ws;
  auto carve = [&](size_t bytes) {
    void* r = (void*)p;
    p += (bytes + 255) & ~(size_t)255;
    return r;
  };
  int* flag     = (int*)carve(256);
  float* params = (float*)carve((size_t)PARAMS_TOTAL * 4);
  int* deg      = (int*)carve((size_t)N * 4);
  int* rowptr   = (int*)carve((size_t)(N + 1) * 4);
  int* cursor   = (int*)carve((size_t)N * 4);
  int* colsrc   = (int*)carve((size_t)E * 4);
  float* h      = (float*)carve((size_t)N * HIDDIM * 4);
  float* skip0  = (float*)carve((size_t)N * HIDDIM * 4);
  float* skip1  = (float*)carve((size_t)N * HIDDIM * 4);
  float* fs     = (float*)carve((size_t)N * HIDDIM * 4);  // aliases xc pre-layers
  float* fd     = (float*)carve((size_t)N * HIDDIM * 4);  // aliases tc pre-layers

  // 1. dtype flag
  detect_dtype<<<1, 256, 0, stream>>>((const unsigned short*)d_in[0], flag);

  // 2. stage all float params to packed fp32
  struct Item { int idx; int off; int n; };
  static const Item items[] = {
    {4,  OFF_W_INIT,    32768}, {5,  OFF_B_INIT,    128},
    {6,  OFF_WSRC_DOWN, 32768}, {7,  OFF_BSRC_DOWN, 256},
    {8,  OFF_WDST_DOWN, 32768}, {9,  OFF_BDST_DOWN, 256},
    {10, OFF_ATTN_DOWN, 256},   {11, OFF_BOUT_DOWN, 256},
    {12, OFF_WSRC_MID,  16384}, {13, OFF_BSRC_MID,  128},
    {14, OFF_WDST_MID,  16384}, {15, OFF_BDST_MID,  128},
    {16, OFF_ATTN_MID,  128},   {17, OFF_BOUT_MID,  128},
    {18, OFF_WSRC_UP,   65536}, {19, OFF_BSRC_UP,   256},
    {20, OFF_WDST_UP,   65536}, {21, OFF_BDST_UP,   256},
    {22, OFF_ATTN_UP,   256},   {23, OFF_BOUT_UP,   256},
    {24, OFF_W_FIN,     16384}, {25, OFF_B_FIN,     128},
  };
  for (const Item& it : items) {
    cvt_to_f32<<<(it.n + 255) / 256, 256, 0, stream>>>(d_in[it.idx], params + it.off, it.n, flag);
  }
  // stage x_t, time_embed into fs/fd (consumed by the init GEMM before reuse)
  float* xc = fs;
  float* tc = fd;
  cvt_to_f32<<<(N * HIDDIM + 255) / 256, 256, 0, stream>>>(d_in[0], xc, N * HIDDIM, flag);
  cvt_to_f32<<<(N * HIDDIM + 255) / 256, 256, 0, stream>>>(d_in[1], tc, N * HIDDIM, flag);

  // 3. CSR by dst (rebuilt every call; ws is re-poisoned)
  hipMemsetAsync(deg, 0, (size_t)N * 4, stream);
  count_deg<<<(E + 255) / 256, 256, 0, stream>>>(dst, deg, E);
  scan_deg<<<1, 1024, 0, stream>>>(deg, rowptr, cursor, N);
  place_edges<<<(E + 255) / 256, 256, 0, stream>>>(src, dst, cursor, colsrc, E);

  dim3 gb((N + MT - 1) / MT);
  dim3 ga((N + 3) / 4);
  const float* P = params;

  // h = gelu([x_t | time_embed] @ W_init + b_init)
  gemm_k<<<gb, 256, 0, stream>>>(xc, 128, tc, 128, P + OFF_W_INIT, P + OFF_B_INIT, h, N, 1);

  auto gat_layer = [&](const float* ha, const float* hb, int Ka, int Kb,
                       const float* Wsrc, const float* bsrc,
                       const float* Wdst, const float* bdst,
                       const float* attn, const float* bout, float* hout) {
    gemm_k<<<gb, 256, 0, stream>>>(ha, Ka, hb, Kb, Wsrc, bsrc, fs, N, 0);
    gemm_k<<<gb, 256, 0, stream>>>(ha, Ka, hb, Kb, Wdst, bdst, fd, N, 0);
    gat_agg<<<ga, 256, 0, stream>>>(fs, fd, rowptr, colsrc, attn, bout, hout, N, E);
  };

  // down 0
  hipMemcpyAsync(skip0, h, (size_t)N * HIDDIM * 4, hipMemcpyDeviceToDevice, stream);
  gat_layer(h, nullptr, 128, 0, P + OFF_WSRC_DOWN, P + OFF_BSRC_DOWN,
            P + OFF_WDST_DOWN, P + OFF_BDST_DOWN, P + OFF_ATTN_DOWN, P + OFF_BOUT_DOWN, h);
  // down 1
  hipMemcpyAsync(skip1, h, (size_t)N * HIDDIM * 4, hipMemcpyDeviceToDevice, stream);
  gat_layer(h, nullptr, 128, 0, P + OFF_WSRC_DOWN + 16384, P + OFF_BSRC_DOWN + 128,
            P + OFF_WDST_DOWN + 16384, P + OFF_BDST_DOWN + 128,
            P + OFF_ATTN_DOWN + 128, P + OFF_BOUT_DOWN + 128, h);
  // mid
  gat_layer(h, nullptr, 128, 0, P + OFF_WSRC_MID, P + OFF_BSRC_MID,
            P + OFF_WDST_MID, P + OFF_BDST_MID, P + OFF_ATTN_MID, P + OFF_BOUT_MID, h);
  // up 0: concat([h, skips[1]])
  gat_layer(h, skip1, 128, 128, P + OFF_WSRC_UP, P + OFF_BSRC_UP,
            P + OFF_WDST_UP, P + OFF_BDST_UP, P + OFF_ATTN_UP, P + OFF_BOUT_UP, h);
  // up 1: concat([h, skips[0]])
  gat_layer(h, skip0, 128, 128, P + OFF_WSRC_UP + 32768, P + OFF_BSRC_UP + 128,
            P + OFF_WDST_UP + 32768, P + OFF_BDST_UP + 128,
            P + OFF_ATTN_UP + 128, P + OFF_BOUT_UP + 128, h);

  // out = h @ W_fin + b_fin -> skip1 (dead), then store (out, h) per dtype flag
  float* outg = skip1;
  gemm_k<<<gb, 256, 0, stream>>>(h, 128, nullptr, 0, P + OFF_W_FIN, P + OFF_B_FIN, outg, N, 0);
  store_out<<<(N * HIDDIM + 255) / 256, 256, 0, stream>>>(outg, h, d_out, N * HIDDIM, flag);
}

// Round 8
// 1351.920 us; speedup vs baseline: 1.3430x; 1.1514x over previous
//
#include <hip/hip_runtime.h>
#include <hip/hip_bf16.h>
#include <math.h>

#define HIDDIM 128
#define MT 64

__device__ inline float gelu_f(float x) {
  // jax.nn.gelu default approximate=True (tanh form)
  float x3 = x * x * x;
  return 0.5f * x * (1.0f + tanhf(0.7978845608028654f * (x + 0.044715f * x3)));
}

// Detect whether float tensors are fp32 (flag=1) or bf16 (flag=0).
__global__ void detect_dtype(const unsigned short* __restrict__ raw, int* __restrict__ flag) {
  __shared__ int cnt;
  if (threadIdx.x == 0) cnt = 0;
  __syncthreads();
  int c = 0;
  for (int i = threadIdx.x; i < 8192; i += 256) {
    int ex = (raw[i] >> 7) & 0xFF;
    if (ex >= 0xC0) c++;
  }
  atomicAdd(&cnt, c);
  __syncthreads();
  if (threadIdx.x == 0) flag[0] = (cnt > 64) ? 1 : 0;
}

__global__ void cvt_to_f32(const void* __restrict__ in, float* __restrict__ out,
                           int n, const int* __restrict__ flag) {
  int i = blockIdx.x * 256 + threadIdx.x;
  if (i < n) {
    out[i] = flag[0] ? ((const float*)in)[i]
                     : __bfloat162float(((const __hip_bfloat16*)in)[i]);
  }
}

// ---- fused param staging: all 22 weight/bias tensors in ONE dispatch ----
#define NITEMS 22
struct StageArgs {
  const void* src[NITEMS];
  int off[NITEMS];    // dest offset in params (floats)
  int n[NITEMS];      // element count
  int blk0[NITEMS];   // first block id of this item
};
__global__ void stage_params(StageArgs a, float* __restrict__ params,
                             const int* __restrict__ flag) {
  int b = blockIdx.x;
  int it = 0;
  while (it + 1 < NITEMS && a.blk0[it + 1] <= b) ++it;
  int i = (b - a.blk0[it]) * 256 + threadIdx.x;
  if (i < a.n[it]) {
    params[a.off[it] + i] = flag[0]
        ? ((const float*)a.src[it])[i]
        : __bfloat162float(((const __hip_bfloat16*)a.src[it])[i]);
  }
}

// ---------------- prefetched (2-barrier K-loop) fused GEMM ----------------
// C[M x NCOL] = act( A[M x KT*32] @ W + bias ), NCOL = FUSED?256:128.
// A row stride is always 128: KT==8 means A = [A1 | A2] with 128 cols each.
// FUSED: cols 0-127 from W0/b0 -> C0, cols 128-255 from W1/b1 -> C1.
// Per block: 64 rows; thread t: rows rg*8..+7 (rg=t>>5), cols cg*4 (+128) (cg=t&31).
template <int KT, int FUSED, int ACT>
__global__ __launch_bounds__(256) void gemm_f(
    const float* __restrict__ A1, const float* __restrict__ A2,
    const float* __restrict__ W0, const float* __restrict__ W1,
    const float* __restrict__ b0, const float* __restrict__ b1,
    float* __restrict__ C0, float* __restrict__ C1, int M) {
  constexpr int NC = FUSED ? 256 : 128;
  constexpr int NW = FUSED ? 8 : 4;    // W float4 prefetches per thread
  __shared__ float As[64][32];
  __shared__ float Ws[32][NC];
  const int t = threadIdx.x;
  const int cg = t & 31, rg = t >> 5;
  const int m0 = blockIdx.x * 64;

  float4 Areg[2], Wreg[NW];
  // prefetch chunk 0
  {
    const float* Ab = A1;
#pragma unroll
    for (int i = 0; i < 2; ++i) {
      int f = t + i * 256, row = f >> 3, kc = f & 7;
      int gr = min(m0 + row, M - 1);
      Areg[i] = *(const float4*)&Ab[(size_t)gr * 128 + kc * 4];
    }
#pragma unroll
    for (int i = 0; i < NW; ++i) {
      int f = t + i * 256;
      int kk = f >> (FUSED ? 6 : 5), c4 = f & (FUSED ? 63 : 31);
      const float* Wb = (FUSED && c4 >= 32) ? W1 : W0;
      int cc = (FUSED && c4 >= 32) ? (c4 - 32) : c4;
      Wreg[i] = *(const float4*)&Wb[(size_t)kk * 128 + cc * 4];
    }
  }

  float4 acc[8][FUSED ? 2 : 1];
#pragma unroll
  for (int r = 0; r < 8; ++r)
#pragma unroll
    for (int h = 0; h < (FUSED ? 2 : 1); ++h)
      acc[r][h] = make_float4(0.f, 0.f, 0.f, 0.f);

  for (int s = 0; s < KT; ++s) {
    __syncthreads();   // previous compute done: LDS free to overwrite
    // write prefetched tiles to LDS
#pragma unroll
    for (int i = 0; i < 2; ++i) {
      int f = t + i * 256, row = f >> 3, kc = f & 7;
      *(float4*)&As[row][kc * 4] = Areg[i];
    }
#pragma unroll
    for (int i = 0; i < NW; ++i) {
      int f = t + i * 256;
      int kk = f >> (FUSED ? 6 : 5), c4 = f & (FUSED ? 63 : 31);
      *(float4*)&Ws[kk][c4 * 4] = Wreg[i];
    }
    // issue next chunk's global loads (in flight during compute)
    if (s + 1 < KT) {
      int sn = s + 1;
      const float* Ab = (KT == 8 && sn >= 4) ? A2 : A1;
      int krel = (sn & 3) * 32;
#pragma unroll
      for (int i = 0; i < 2; ++i) {
        int f = t + i * 256, row = f >> 3, kc = f & 7;
        int gr = min(m0 + row, M - 1);
        Areg[i] = *(const float4*)&Ab[(size_t)gr * 128 + krel + kc * 4];
      }
#pragma unroll
      for (int i = 0; i < NW; ++i) {
        int f = t + i * 256;
        int kk = f >> (FUSED ? 6 : 5), c4 = f & (FUSED ? 63 : 31);
        const float* Wb = (FUSED && c4 >= 32) ? W1 : W0;
        int cc = (FUSED && c4 >= 32) ? (c4 - 32) : c4;
        Wreg[i] = *(const float4*)&Wb[(size_t)(sn * 32 + kk) * 128 + cc * 4];
      }
    }
    __syncthreads();   // LDS tiles visible
    // compute chunk
#pragma unroll
    for (int k4 = 0; k4 < 8; ++k4) {
      float4 a[8];
#pragma unroll
      for (int r = 0; r < 8; ++r) a[r] = *(const float4*)&As[rg * 8 + r][k4 * 4];
#pragma unroll
      for (int kk = 0; kk < 4; ++kk) {
        float4 w0 = *(const float4*)&Ws[k4 * 4 + kk][cg * 4];
        float4 w1;
        if (FUSED) w1 = *(const float4*)&Ws[k4 * 4 + kk][128 + cg * 4];
#pragma unroll
        for (int r = 0; r < 8; ++r) {
          float av = (kk == 0) ? a[r].x : (kk == 1) ? a[r].y : (kk == 2) ? a[r].z : a[r].w;
          acc[r][0].x = fmaf(av, w0.x, acc[r][0].x);
          acc[r][0].y = fmaf(av, w0.y, acc[r][0].y);
          acc[r][0].z = fmaf(av, w0.z, acc[r][0].z);
          acc[r][0].w = fmaf(av, w0.w, acc[r][0].w);
          if (FUSED) {
            acc[r][1].x = fmaf(av, w1.x, acc[r][1].x);
            acc[r][1].y = fmaf(av, w1.y, acc[r][1].y);
            acc[r][1].z = fmaf(av, w1.z, acc[r][1].z);
            acc[r][1].w = fmaf(av, w1.w, acc[r][1].w);
          }
        }
      }
    }
  }

  // epilogue
  float4 bias0 = *(const float4*)&b0[cg * 4];
  float4 bias1;
  if (FUSED) bias1 = *(const float4*)&b1[cg * 4];
#pragma unroll
  for (int r = 0; r < 8; ++r) {
    int row = m0 + rg * 8 + r;
    if (row < M) {
      float4 v = acc[r][0];
      v.x += bias0.x; v.y += bias0.y; v.z += bias0.z; v.w += bias0.w;
      if (ACT) { v.x = gelu_f(v.x); v.y = gelu_f(v.y); v.z = gelu_f(v.z); v.w = gelu_f(v.w); }
      *(float4*)&C0[(size_t)row * 128 + cg * 4] = v;
      if (FUSED) {
        float4 u = acc[r][1];
        u.x += bias1.x; u.y += bias1.y; u.z += bias1.z; u.w += bias1.w;
        *(float4*)&C1[(size_t)row * 128 + cg * 4] = u;
      }
    }
  }
}

// ---------------- CSR build (R2/R7-proven) ----------------
__global__ void count_deg(const int* __restrict__ dst, int* __restrict__ deg, int E) {
  int e = blockIdx.x * 256 + threadIdx.x;
  if (e < E) atomicAdd(&deg[dst[e]], 1);
}

__global__ __launch_bounds__(1024) void scan_deg(const int* __restrict__ deg,
                                                 int* __restrict__ rowptr,
                                                 int* __restrict__ cursor, int N) {
  __shared__ int buf[1024];
  __shared__ int carry;
  if (threadIdx.x == 0) carry = 0;
  __syncthreads();
  for (int base = 0; base < N; base += 1024) {
    int i = base + threadIdx.x;
    int v = (i < N) ? deg[i] : 0;
    buf[threadIdx.x] = v;
    __syncthreads();
    for (int off = 1; off < 1024; off <<= 1) {
      int add = (threadIdx.x >= (unsigned)off) ? buf[threadIdx.x - off] : 0;
      __syncthreads();
      buf[threadIdx.x] += add;
      __syncthreads();
    }
    int excl = buf[threadIdx.x] - v + carry;
    if (i < N) { rowptr[i] = excl; cursor[i] = excl; }
    __syncthreads();
    if (threadIdx.x == 0) carry += buf[1023];
    __syncthreads();
  }
  if (threadIdx.x == 0) rowptr[N] = carry;
}

__global__ void place_edges(const int* __restrict__ src, const int* __restrict__ dst,
                            int* __restrict__ cursor, int* __restrict__ colsrc, int E) {
  int e = blockIdx.x * 256 + threadIdx.x;
  if (e < E) {
    int pos = atomicAdd(&cursor[dst[e]], 1);
    colsrc[pos] = src[e];
  }
}

// ---------------- GATv2 aggregation (R7-proven) ----------------
__global__ __launch_bounds__(256) void gat_agg(
    const float* __restrict__ fs, const float* __restrict__ fd,
    const int* __restrict__ rowptr, const int* __restrict__ colsrc,
    const float* __restrict__ attn, const float* __restrict__ bout,
    float* __restrict__ hout, int N, int E) {
  int wv = threadIdx.x >> 6, lane = threadIdx.x & 63;
  int n = blockIdx.x * 4 + wv;
  if (n >= N) return;
  int half = lane >> 5;
  int fb = (lane & 31) * 4;
  float4 fdv = *(const float4*)&fd[(size_t)n * HIDDIM + fb];
  float a0 = attn[fb], a1 = attn[fb + 1], a2 = attn[fb + 2], a3 = attn[fb + 3];
  int e0 = rowptr[n], e1 = rowptr[n + 1];
  e0 = max(0, min(e0, E));
  e1 = max(e0, min(e1, E));
  float s = 0.f, ax = 0.f, ay = 0.f, az = 0.f, aw = 0.f;
  for (int c0 = e0; c0 < e1; c0 += 64) {
    int cn = min(64, e1 - c0);
    int myidx = (lane < cn) ? colsrc[c0 + lane] : 0;
    myidx = ((unsigned)myidx < (unsigned)N) ? myidx : 0;
    int iters = (cn + 3) >> 2;
    for (int it = 0; it < iters; ++it) {
      int jA = 4 * it + half;
      int jB = jA + 2;
      int sA = __shfl(myidx, min(jA, cn - 1));
      int sB = __shfl(myidx, min(jB, cn - 1));
      float4 fA = *(const float4*)&fs[(size_t)sA * HIDDIM + fb];
      float4 fB = *(const float4*)&fs[(size_t)sB * HIDDIM + fb];
      float v0, v1, v2, v3, lA, lB;
      v0 = fA.x + fdv.x; v0 = v0 > 0.f ? v0 : 0.2f * v0;
      v1 = fA.y + fdv.y; v1 = v1 > 0.f ? v1 : 0.2f * v1;
      v2 = fA.z + fdv.z; v2 = v2 > 0.f ? v2 : 0.2f * v2;
      v3 = fA.w + fdv.w; v3 = v3 > 0.f ? v3 : 0.2f * v3;
      lA = fmaf(v0, a0, fmaf(v1, a1, fmaf(v2, a2, v3 * a3)));
      v0 = fB.x + fdv.x; v0 = v0 > 0.f ? v0 : 0.2f * v0;
      v1 = fB.y + fdv.y; v1 = v1 > 0.f ? v1 : 0.2f * v1;
      v2 = fB.z + fdv.z; v2 = v2 > 0.f ? v2 : 0.2f * v2;
      v3 = fB.w + fdv.w; v3 = v3 > 0.f ? v3 : 0.2f * v3;
      lB = fmaf(v0, a0, fmaf(v1, a1, fmaf(v2, a2, v3 * a3)));
      lA += __shfl_xor(lA, 1); lA += __shfl_xor(lA, 2); lA += __shfl_xor(lA, 4);
      lB += __shfl_xor(lB, 1); lB += __shfl_xor(lB, 2); lB += __shfl_xor(lB, 4);
      lA = fminf(lA, 60.f);
      lB = fminf(lB, 60.f);
      float pA = (jA < cn) ? __expf(lA) : 0.f;
      float pB = (jB < cn) ? __expf(lB) : 0.f;
      s += pA + pB;
      ax = fmaf(pA, fA.x, fmaf(pB, fB.x, ax));
      ay = fmaf(pA, fA.y, fmaf(pB, fB.y, ay));
      az = fmaf(pA, fA.z, fmaf(pB, fB.z, az));
      aw = fmaf(pA, fA.w, fmaf(pB, fB.w, aw));
    }
  }
  s += __shfl_xor(s, 32);
  ax += __shfl_xor(ax, 32); ay += __shfl_xor(ay, 32);
  az += __shfl_xor(az, 32); aw += __shfl_xor(aw, 32);
  if (half == 0) {
    float inv = 1.f / (s + 1e-9f);
    float o0 = gelu_f(fmaf(ax, inv, bout[fb]));
    float o1 = gelu_f(fmaf(ay, inv, bout[fb + 1]));
    float o2 = gelu_f(fmaf(az, inv, bout[fb + 2]));
    float o3 = gelu_f(fmaf(aw, inv, bout[fb + 3]));
    *(float4*)&hout[(size_t)n * HIDDIM + fb] = make_float4(o0, o1, o2, o3);
  }
}

__global__ void store_out(const float* __restrict__ og, const float* __restrict__ h,
                          void* __restrict__ dout, int n, const int* __restrict__ flag) {
  int i = blockIdx.x * 256 + threadIdx.x;
  if (i >= n) return;
  if (flag[0]) {
    ((float*)dout)[i] = og[i];
    ((float*)dout)[n + i] = h[i];
  } else {
    ((__hip_bfloat16*)dout)[i] = __float2bfloat16(og[i]);
    ((__hip_bfloat16*)dout)[n + i] = __float2bfloat16(h[i]);
  }
}

// packed fp32 param offsets (floats)
#define OFF_W_INIT    0
#define OFF_B_INIT    32768
#define OFF_WSRC_DOWN 32896
#define OFF_BSRC_DOWN 65664
#define OFF_WDST_DOWN 65920
#define OFF_BDST_DOWN 98688
#define OFF_ATTN_DOWN 98944
#define OFF_BOUT_DOWN 99200
#define OFF_WSRC_MID  99456
#define OFF_BSRC_MID  115840
#define OFF_WDST_MID  115968
#define OFF_BDST_MID  132352
#define OFF_ATTN_MID  132480
#define OFF_BOUT_MID  132608
#define OFF_WSRC_UP   132736
#define OFF_BSRC_UP   198272
#define OFF_WDST_UP   198528
#define OFF_BDST_UP   264064
#define OFF_ATTN_UP   264320
#define OFF_BOUT_UP   264576
#define OFF_W_FIN     264832
#define OFF_B_FIN     281216
#define PARAMS_TOTAL  281344

extern "C" void kernel_launch(void* const* d_in, const int* in_sizes, int n_in,
                              void* d_out, int out_size, void* d_ws, size_t ws_size,
                              hipStream_t stream) {
  const int N = in_sizes[1] / HIDDIM;
  const int E = in_sizes[2];
  const int* src = (const int*)d_in[2];
  const int* dst = (const int*)d_in[3];

  char* p = (char*)d_ws;
  auto carve = [&](size_t bytes) {
    void* r = (void*)p;
    p += (bytes + 255) & ~(size_t)255;
    return r;
  };
  int* flag     = (int*)carve(256);
  float* params = (float*)carve((size_t)PARAMS_TOTAL * 4);
  int* deg      = (int*)carve((size_t)N * 4);
  int* rowptr   = (int*)carve((size_t)(N + 1) * 4);
  int* cursor   = (int*)carve((size_t)N * 4);
  int* colsrc   = (int*)carve((size_t)E * 4);
  float* h      = (float*)carve((size_t)N * HIDDIM * 4);
  float* skip0  = (float*)carve((size_t)N * HIDDIM * 4);
  float* skip1  = (float*)carve((size_t)N * HIDDIM * 4);
  float* fs     = (float*)carve((size_t)N * HIDDIM * 4);
  float* fd     = (float*)carve((size_t)N * HIDDIM * 4);

  // 1. dtype flag
  detect_dtype<<<1, 256, 0, stream>>>((const unsigned short*)d_in[0], flag);

  // 2. stage all params in one dispatch
  static const int idx[NITEMS] = {4,5,6,7,8,9,10,11,12,13,14,15,16,17,18,19,20,21,22,23,24,25};
  static const int off[NITEMS] = {
    OFF_W_INIT, OFF_B_INIT, OFF_WSRC_DOWN, OFF_BSRC_DOWN, OFF_WDST_DOWN, OFF_BDST_DOWN,
    OFF_ATTN_DOWN, OFF_BOUT_DOWN, OFF_WSRC_MID, OFF_BSRC_MID, OFF_WDST_MID, OFF_BDST_MID,
    OFF_ATTN_MID, OFF_BOUT_MID, OFF_WSRC_UP, OFF_BSRC_UP, OFF_WDST_UP, OFF_BDST_UP,
    OFF_ATTN_UP, OFF_BOUT_UP, OFF_W_FIN, OFF_B_FIN};
  static const int cnt[NITEMS] = {
    32768, 128, 32768, 256, 32768, 256, 256, 256, 16384, 128, 16384, 128,
    128, 128, 65536, 256, 65536, 256, 256, 256, 16384, 128};
  StageArgs sa;
  int nb = 0;
  for (int i = 0; i < NITEMS; ++i) {
    sa.src[i] = d_in[idx[i]];
    sa.off[i] = off[i];
    sa.n[i] = cnt[i];
    sa.blk0[i] = nb;
    nb += (cnt[i] + 255) / 256;
  }
  stage_params<<<nb, 256, 0, stream>>>(sa, params, flag);
  // stage x_t, time_embed into fs/fd (consumed by init GEMM before reuse)
  float* xc = fs;
  float* tc = fd;
  cvt_to_f32<<<(N * HIDDIM + 255) / 256, 256, 0, stream>>>(d_in[0], xc, N * HIDDIM, flag);
  cvt_to_f32<<<(N * HIDDIM + 255) / 256, 256, 0, stream>>>(d_in[1], tc, N * HIDDIM, flag);

  // 3. CSR by dst
  hipMemsetAsync(deg, 0, (size_t)N * 4, stream);
  count_deg<<<(E + 255) / 256, 256, 0, stream>>>(dst, deg, E);
  scan_deg<<<1, 1024, 0, stream>>>(deg, rowptr, cursor, N);
  place_edges<<<(E + 255) / 256, 256, 0, stream>>>(src, dst, cursor, colsrc, E);

  dim3 gb((N + MT - 1) / MT);
  dim3 ga((N + 3) / 4);
  const float* P = params;

  // init: h = gelu([x_t | time_embed] @ W_init + b_init)
  gemm_f<8, 0, 1><<<gb, 256, 0, stream>>>(
      xc, tc, P + OFF_W_INIT, nullptr, P + OFF_B_INIT, nullptr, h, nullptr, N);

  auto gat_layer = [&](const float* ha, const float* hb,
                       const float* Wsrc, const float* bsrc,
                       const float* Wdst, const float* bdst,
                       const float* attn, const float* bout, float* hout) {
    if (hb)
      gemm_f<8, 1, 0><<<gb, 256, 0, stream>>>(ha, hb, Wsrc, Wdst, bsrc, bdst, fs, fd, N);
    else
      gemm_f<4, 1, 0><<<gb, 256, 0, stream>>>(ha, nullptr, Wsrc, Wdst, bsrc, bdst, fs, fd, N);
    gat_agg<<<ga, 256, 0, stream>>>(fs, fd, rowptr, colsrc, attn, bout, hout, N, E);
  };

  // down 0
  hipMemcpyAsync(skip0, h, (size_t)N * HIDDIM * 4, hipMemcpyDeviceToDevice, stream);
  gat_layer(h, nullptr, P + OFF_WSRC_DOWN, P + OFF_BSRC_DOWN,
            P + OFF_WDST_DOWN, P + OFF_BDST_DOWN, P + OFF_ATTN_DOWN, P + OFF_BOUT_DOWN, h);
  // down 1
  hipMemcpyAsync(skip1, h, (size_t)N * HIDDIM * 4, hipMemcpyDeviceToDevice, stream);
  gat_layer(h, nullptr, P + OFF_WSRC_DOWN + 16384, P + OFF_BSRC_DOWN + 128,
            P + OFF_WDST_DOWN + 16384, P + OFF_BDST_DOWN + 128,
            P + OFF_ATTN_DOWN + 128, P + OFF_BOUT_DOWN + 128, h);
  // mid
  gat_layer(h, nullptr, P + OFF_WSRC_MID, P + OFF_BSRC_MID,
            P + OFF_WDST_MID, P + OFF_BDST_MID, P + OFF_ATTN_MID, P + OFF_BOUT_MID, h);
  // up 0: concat([h, skip1])
  gat_layer(h, skip1, P + OFF_WSRC_UP, P + OFF_BSRC_UP,
            P + OFF_WDST_UP, P + OFF_BDST_UP, P + OFF_ATTN_UP, P + OFF_BOUT_UP, h);
  // up 1: concat([h, skip0])
  gat_layer(h, skip0, P + OFF_WSRC_UP + 32768, P + OFF_BSRC_UP + 128,
            P + OFF_WDST_UP + 32768, P + OFF_BDST_UP + 128,
            P + OFF_ATTN_UP + 128, P + OFF_BOUT_UP + 128, h);

  // fin: out = h @ W_fin + b_fin -> skip1 (dead), then dtype-aware store
  float* outg = skip1;
  gemm_f<4, 0, 0><<<gb, 256, 0, stream>>>(
      h, nullptr, P + OFF_W_FIN, nullptr, P + OFF_B_FIN, nullptr, outg, nullptr, N);
  store_out<<<(N * HIDDIM + 255) / 256, 256, 0, stream>>>(outg, h, d_out, N * HIDDIM, flag);
}